// Round 18
// baseline (100.852 us; speedup 1.0000x reference)
//
#include <hip/hip_runtime.h>
#include <math.h>

// Problem constants: B=8, N=4096, C=768, H=W=64, GROUPS=4.
#define BB 8
#define CC 768
#define HH 64
#define WW 64
#define NN 4096
#define GG 4
#define KK 1536            /* g2 row: [gelu 768 | x 768] fp16 */
#define TPAD 1552          /* LDS row stride in halves: 97 words = 1 mod 32 */

typedef __attribute__((ext_vector_type(8))) _Float16 half8;
typedef __attribute__((ext_vector_type(4))) float f32x4;

// tanh-form GELU, exp2-folded.
__device__ __forceinline__ float gelu_fast(float v) {
    const float z2 = 2.3022223f * v * fmaf(0.044715f, v * v, 1.0f);
    const float e = __builtin_amdgcn_exp2f(-z2);
    return __fdividef(v, 1.0f + e);
}

// ---------------------------------------------------------------------------
// K0: convert off_w / wt_w (8x768 fp32 each) to fp16 once per call.
// w16 layout: [0][o][c] = off_w, [1][o][c] = wt_w.
// ---------------------------------------------------------------------------
__global__ __launch_bounds__(256) void dq_wcvt(
    const float* __restrict__ off_w, const float* __restrict__ wt_w,
    _Float16* __restrict__ w16)
{
    const int i = blockIdx.x * 256 + threadIdx.x;   // 12288 total
    if (i < 8 * CC) w16[i] = (_Float16)off_w[i];
    else            w16[i] = (_Float16)(wt_w[i - 8 * CC]);
}

// ---------------------------------------------------------------------------
// K1: PURE streaming conv+GELU (r17's A1 phase-1 with the MFMA consumer cut
// out - 17 rounds showed the welded conv+MFMA kernel stalls at ~60us with no
// binding resource; make the producer memory-bound instead).
// Thread = (b, row h, channel c); 64-col sliding 3x3 window, batch-8 register
// prefetch; writes gelu AND center-x as fp16 to g2[pos][KK]. 256-thr blocks,
// grid 1536 = 8 xcd x 64 rows x 3 strips, XCD-slab swizzled (halo L2 reuse).
// No LDS, no barriers, no MFMA.
// ---------------------------------------------------------------------------
__global__ __launch_bounds__(256) void dq_conv(
    const float* __restrict__ x,      // (B, N, C)
    const float* __restrict__ dw_w,   // (C, 9)
    const float* __restrict__ dw_b,   // (C,)
    _Float16* __restrict__ g2)        // (B*N, KK)
{
    const int t = threadIdx.x;
    const int xcd = blockIdx.x & 7;
    const int local = blockIdx.x >> 3;        // 0..191
    const int strip = local % 3;
    const int r = xcd * (BB * HH / 8) + local / 3;   // global row 0..511
    const int h = r & (HH - 1);
    const int b = r >> 6;
    const int c = strip * 256 + t;

    float w9[9];
#pragma unroll
    for (int j = 0; j < 9; ++j) w9[j] = dw_w[c * 9 + j];
    const float bias = dw_b[c];
    const bool tv = (h > 0), bv = (h < HH - 1);
    const float wt0 = tv ? w9[0] : 0.f, wt1 = tv ? w9[1] : 0.f, wt2 = tv ? w9[2] : 0.f;
    const float wb0 = bv ? w9[6] : 0.f, wb1 = bv ? w9[7] : 0.f, wb2 = bv ? w9[8] : 0.f;

    const float* base = x + (size_t)b * NN * CC + c;
    const float* rT = base + (size_t)((tv ? h - 1 : 0) * WW) * CC;
    const float* rM = base + (size_t)(h * WW) * CC;
    const float* rB = base + (size_t)((bv ? h + 1 : h) * WW) * CC;

    _Float16* grow = g2 + (size_t)(b * NN + h * WW) * KK + c;

    float cT[8], cM[8], cB[8], nT[8], nM[8], nB[8];
    float pT = 0.f, pM = 0.f, pB = 0.f;

#pragma unroll
    for (int j = 0; j < 8; ++j) {
        const size_t o = (size_t)j * CC;
        cT[j] = rT[o]; cM[j] = rM[o]; cB[j] = rB[o];
    }

#pragma unroll
    for (int wb = 0; wb < 8; ++wb) {
        if (wb < 7) {
#pragma unroll
            for (int j = 0; j < 8; ++j) {
                const size_t o = (size_t)(wb * 8 + 8 + j) * CC;
                nT[j] = rT[o]; nM[j] = rM[o]; nB[j] = rB[o];
            }
        } else {
#pragma unroll
            for (int j = 0; j < 8; ++j) { nT[j] = 0.f; nM[j] = 0.f; nB[j] = 0.f; }
        }
#pragma unroll
        for (int j = 0; j < 8; ++j) {
            const float lT = j ? cT[j - 1] : pT;
            const float lM = j ? cM[j - 1] : pM;
            const float lB = j ? cB[j - 1] : pB;
            const float rTv = (j == 7) ? nT[0] : cT[j + 1];
            const float rMv = (j == 7) ? nM[0] : cM[j + 1];
            const float rBv = (j == 7) ? nB[0] : cB[j + 1];
            const float conv = lT * wt0 + cT[j] * wt1 + rTv * wt2
                             + lM * w9[3] + cM[j] * w9[4] + rMv * w9[5]
                             + lB * wb0 + cB[j] * wb1 + rBv * wb2;
            const size_t po = (size_t)(wb * 8 + j) * KK;
            grow[po]       = (_Float16)gelu_fast(conv + bias);
            grow[po + CC]  = (_Float16)cM[j];
        }
        pT = cT[7]; pM = cM[7]; pB = cB[7];
#pragma unroll
        for (int j = 0; j < 8; ++j) { cT[j] = nT[j]; cM[j] = nM[j]; cB[j] = nB[j]; }
    }
}

// ---------------------------------------------------------------------------
// K2: einsum + coords, FULL K per block (no partials, no combine kernel).
// Block = 16 consecutive positions (same b, h), 128 threads (2 waves).
// Stage 16 x KK fp16 rows into LDS (48.5KB + pad, coalesced 3KB rows);
// wave0 = gelu x off_w (K=768, 24 MFMA), wave1 = x x wt_w. wave1 posts wt
// sums through LDS; wave0 applies sigmoid gate + shift + clip and writes
// ixiy directly. Kills the 12.6MB offpart round-trip and dq_combine.
// ---------------------------------------------------------------------------
__global__ __launch_bounds__(128) void dq_gemm(
    const _Float16* __restrict__ g2,    // (B*N, KK)
    const _Float16* __restrict__ w16,   // (2, 8, CC)
    const float* __restrict__ off_b,
    const float* __restrict__ wt_b,
    float* __restrict__ ixiy)           // (2, B*G, N)
{
    __shared__ __attribute__((aligned(16))) _Float16 tile[16][TPAD];  // 48.5 KB
    __shared__ float exw[16][8];
    const int t = threadIdx.x;
    const int lane = t & 63, wv = t >> 6;
    const int p0 = blockIdx.x * 16;
    const int b = p0 >> 12;
    const int hw0 = p0 & 4095;
    const int h = hw0 >> 6, w0 = hw0 & 63;

    // stage: 16 rows x 192 half8-chunks, 128 threads -> 24 iters
    const half8* src = (const half8*)(g2 + (size_t)p0 * KK);
#pragma unroll
    for (int it = 0; it < 24; ++it) {
        const int ci = it * 128 + t;
        const int row = ci / 192, col = ci % 192;
        *(half8*)&tile[row][col * 8] = src[(size_t)row * 192 + col];
    }
    __syncthreads();

    const int n = lane & 15, kg = lane >> 4;
    const bool valid = (n < 8);
    const int koff = wv * CC;                       // wave0: gelu, wave1: x
    const _Float16* wrow = w16 + (size_t)wv * 8 * CC + (valid ? n : 0) * CC;

    f32x4 acc = {0.f, 0.f, 0.f, 0.f};
#pragma unroll
    for (int kt = 0; kt < 24; ++kt) {
        const half8 a = *(const half8*)&tile[n][koff + kt * 32 + kg * 8];
        const half8 bf = *(const half8*)&wrow[kt * 32 + kg * 8];
        acc = __builtin_amdgcn_mfma_f32_16x16x32_f16(a, bf, acc, 0, 0, 0);
    }

    // D: col n = output o (n<8 valid), rows kg*4+j = positions p0+kg*4+j
    if (wv == 1 && valid) {
#pragma unroll
        for (int j = 0; j < 4; ++j) exw[kg * 4 + j][n] = acc[j];
    }
    __syncthreads();
    if (wv == 0 && valid) {
        const float ob = off_b[n], wbv = wt_b[n];
#pragma unroll
        for (int j = 0; j < 4; ++j) {
            const int pos = kg * 4 + j;
            const float wt = exw[pos][n];
            const float sig = __fdividef(1.f, 1.f + __builtin_amdgcn_exp2f(-1.4426950f * (wt + wbv)));
            const float val = (acc[j] + ob) * sig;
            const int w = w0 + pos;
            const int hwp = h * WW + w;
            if (n < 4) {
                const float shx = (n == 2) ? -1.f : ((n == 3) ? 1.f : 0.f);
                ixiy[(b * GG + n) * NN + hwp] = fminf(fmaxf((float)w + val + shx, 0.f), (float)(WW - 1));
            } else {
                const int g = n - 4;
                const float shy = (g == 0) ? -1.f : ((g == 1) ? 1.f : 0.f);
                ixiy[BB * GG * NN + (b * GG + g) * NN + hwp] = fminf(fmaxf((float)h + val + shy, 0.f), (float)(HH - 1));
            }
        }
    }
}

// ---------------------------------------------------------------------------
// B: bilinear border sampling, float4-vectorized, XCD-swizzled (T1).
// ---------------------------------------------------------------------------
__global__ __launch_bounds__(192) void dq_sample_vec(
    const float* __restrict__ x,        // (B, N, C)
    const float* __restrict__ ixiy,     // (2, B*G, N)
    float* __restrict__ out)            // (B, N, C)
{
    __shared__ float ixy[8];
    const int t = threadIdx.x;
    const int p = (blockIdx.x & 7) * (BB * NN / 8) + (blockIdx.x >> 3);
    const int b = p >> 12;
    const int hw = p & 4095;

    if (t < 8) {
        const int g = t & 3;
        const int plane = (t >> 2) * (BB * GG * NN);
        ixy[t] = ixiy[plane + (b * GG + g) * NN + hw];
    }
    __syncthreads();

    const int g = t / 48;
    const float ix = ixy[g], iy = ixy[4 + g];
    const float x0f = floorf(ix), y0f = floorf(iy);
    const float wx = ix - x0f, wy = iy - y0f;
    const int x0 = (int)x0f, y0 = (int)y0f;
    const int x1 = min(x0 + 1, WW - 1), y1 = min(y0 + 1, HH - 1);
    const int c4 = t * 4;
    const float* xb = x + (size_t)b * NN * CC;
    const float4 v00 = *(const float4*)(xb + (size_t)(y0 * WW + x0) * CC + c4);
    const float4 v01 = *(const float4*)(xb + (size_t)(y0 * WW + x1) * CC + c4);
    const float4 v10 = *(const float4*)(xb + (size_t)(y1 * WW + x0) * CC + c4);
    const float4 v11 = *(const float4*)(xb + (size_t)(y1 * WW + x1) * CC + c4);
    const float w00 = (1.f - wx) * (1.f - wy), w01 = wx * (1.f - wy);
    const float w10 = (1.f - wx) * wy,         w11 = wx * wy;
    float4 rr;
    rr.x = v00.x * w00 + v01.x * w01 + v10.x * w10 + v11.x * w11;
    rr.y = v00.y * w00 + v01.y * w01 + v10.y * w10 + v11.y * w11;
    rr.z = v00.z * w00 + v01.z * w01 + v10.z * w10 + v11.z * w11;
    rr.w = v00.w * w00 + v01.w * w01 + v10.w * w10 + v11.w * w11;
    *(float4*)(out + (size_t)p * CC + c4) = rr;
}

// ---------------------------------------------------------------------------
// Fallback (small ws): round-1 fused offsets kernel + scalar sampler.
// ---------------------------------------------------------------------------
__global__ __launch_bounds__(256) void dqshift_offsets_kernel(
    const float* __restrict__ x, const float* __restrict__ dw_w,
    const float* __restrict__ dw_b, const float* __restrict__ off_w,
    const float* __restrict__ off_b, const float* __restrict__ wt_w,
    const float* __restrict__ wt_b, float* __restrict__ ixiy)
{
    const int wave = threadIdx.x >> 6;
    const int lane = threadIdx.x & 63;
    const int p = blockIdx.x * 4 + wave;
    const int b = p >> 12;
    const int hw = p & 4095;
    const int h = hw >> 6;
    const int w = hw & 63;
    const float* xb = x + (size_t)b * NN * CC;
    float accO[8], accW[8];
#pragma unroll
    for (int o = 0; o < 8; ++o) { accO[o] = 0.f; accW[o] = 0.f; }
    for (int k = 0; k < CC / 64; ++k) {
        const int c = lane + (k << 6);
        float conv = 0.f, xc = 0.f;
#pragma unroll
        for (int dy = -1; dy <= 1; ++dy) {
            const int hh = h + dy;
            const bool vy = (hh >= 0) && (hh < HH);
#pragma unroll
            for (int dx = -1; dx <= 1; ++dx) {
                const int ww = w + dx;
                const bool vv = vy && (ww >= 0) && (ww < WW);
                const float tt = vv ? xb[(size_t)(hh * WW + ww) * CC + c] : 0.f;
                if (dy == 0 && dx == 0) xc = tt;
                conv = fmaf(tt, dw_w[c * 9 + (dy + 1) * 3 + (dx + 1)], conv);
            }
        }
        const float gv = conv + dw_b[c];
        const float gle = 0.5f * gv * (1.0f + erff(gv * 0.70710678118654752f));
#pragma unroll
        for (int o = 0; o < 8; ++o) {
            accO[o] = fmaf(gle, off_w[o * CC + c], accO[o]);
            accW[o] = fmaf(xc, wt_w[o * CC + c], accW[o]);
        }
    }
#pragma unroll
    for (int o = 0; o < 8; ++o) {
#pragma unroll
        for (int s = 32; s > 0; s >>= 1) {
            accO[o] += __shfl_xor(accO[o], s, 64);
            accW[o] += __shfl_xor(accW[o], s, 64);
        }
    }
    if (lane == 0) {
        const float shx[4] = {0.f, 0.f, -1.f, 1.f};
        const float shy[4] = {-1.f, 1.f, 0.f, 0.f};
#pragma unroll
        for (int g = 0; g < 4; ++g) {
            const float sx = 1.f / (1.f + expf(-(accW[g] + wt_b[g])));
            const float sy = 1.f / (1.f + expf(-(accW[4 + g] + wt_b[4 + g])));
            const float ox = (accO[g] + off_b[g]) * sx + shx[g];
            const float oy = (accO[4 + g] + off_b[4 + g]) * sy + shy[g];
            const float ix = fminf(fmaxf((float)w + ox, 0.f), (float)(WW - 1));
            const float iy = fminf(fmaxf((float)h + oy, 0.f), (float)(HH - 1));
            const int idx = (b * GG + g) * NN + hw;
            ixiy[idx] = ix;
            ixiy[BB * GG * NN + idx] = iy;
        }
    }
}

__global__ __launch_bounds__(256) void dqshift_sample_kernel(
    const float* __restrict__ x,
    const float* __restrict__ ixiy,
    float* __restrict__ out)
{
    const int p = blockIdx.x;
    const int b = p >> 12;
    const int hw = p & 4095;
    const float* xb = x + (size_t)b * NN * CC;
    float* ob = out + (size_t)p * CC;

#pragma unroll
    for (int k = 0; k < 3; ++k) {
        const int c = threadIdx.x + (k << 8);
        const int g = c / (CC / GG);
        const int idx = (b * GG + g) * NN + hw;
        const float ix = ixiy[idx];
        const float iy = ixiy[BB * GG * NN + idx];
        const float x0f = floorf(ix);
        const float y0f = floorf(iy);
        const float wx = ix - x0f;
        const float wy = iy - y0f;
        const int x0 = (int)x0f;
        const int y0 = (int)y0f;
        const int x1 = min(x0 + 1, WW - 1);
        const int y1 = min(y0 + 1, HH - 1);
        const float* r0 = xb + (size_t)(y0 * WW) * CC + c;
        const float* r1 = xb + (size_t)(y1 * WW) * CC + c;
        const float v00 = r0[(size_t)x0 * CC];
        const float v01 = r0[(size_t)x1 * CC];
        const float v10 = r1[(size_t)x0 * CC];
        const float v11 = r1[(size_t)x1 * CC];
        ob[c] = v00 * (1.f - wx) * (1.f - wy) + v01 * wx * (1.f - wy)
              + v10 * (1.f - wx) * wy + v11 * wx * wy;
    }
}

extern "C" void kernel_launch(void* const* d_in, const int* in_sizes, int n_in,
                              void* d_out, int out_size, void* d_ws, size_t ws_size,
                              hipStream_t stream) {
    const float* x     = (const float*)d_in[0];
    const float* dw_w  = (const float*)d_in[1];
    const float* dw_b  = (const float*)d_in[2];
    const float* off_w = (const float*)d_in[3];
    const float* off_b = (const float*)d_in[4];
    const float* wt_w  = (const float*)d_in[5];
    const float* wt_b  = (const float*)d_in[6];

    // ws layout: ixiy (1 MiB) | w16 (24 KiB, padded to 32 KiB) | g2 (100.7 MiB)
    float* ixiy = (float*)d_ws;
    _Float16* w16 = (_Float16*)((char*)d_ws + 1048576);
    _Float16* g2  = (_Float16*)((char*)d_ws + 1048576 + 32768);
    const size_t need = 1048576 + 32768 + (size_t)BB * NN * KK * 2;

    if (ws_size >= need) {
        dq_wcvt<<<48, 256, 0, stream>>>(off_w, wt_w, w16);
        dq_conv<<<BB * HH * 3, 256, 0, stream>>>(x, dw_w, dw_b, g2);
        dq_gemm<<<BB * NN / 16, 128, 0, stream>>>(g2, w16, off_b, wt_b, ixiy);
        dq_sample_vec<<<BB * NN, 192, 0, stream>>>(x, ixiy, (float*)d_out);
    } else {
        dqshift_offsets_kernel<<<BB * NN / 4, 256, 0, stream>>>(
            x, dw_w, dw_b, off_w, off_b, wt_w, wt_b, ixiy);
        dqshift_sample_kernel<<<BB * NN, 256, 0, stream>>>(x, ixiy, (float*)d_out);
    }
}

// Round 19
// 88.495 us; speedup vs baseline: 1.1396x; 1.1396x over previous
//
#include <hip/hip_runtime.h>
#include <math.h>

// Problem constants: B=8, N=4096, C=768, H=W=64, GROUPS=4.
#define BB 8
#define CC 768
#define HH 64
#define WW 64
#define NN 4096
#define GG 4
#define NCHUNK 3
#define CHUNK 256   /* channels per A1 block: 128 threads x 2 ch (float2 loads) */

typedef __attribute__((ext_vector_type(8))) _Float16 half8;
typedef __attribute__((ext_vector_type(2))) _Float16 half2f;
typedef __attribute__((ext_vector_type(4))) float f32x4;

// tanh-form GELU, exp2-folded.
__device__ __forceinline__ float gelu_fast(float v) {
    const float z2 = 2.3022223f * v * fmaf(0.044715f, v * v, 1.0f);
    const float e = __builtin_amdgcn_exp2f(-z2);
    return __fdividef(v, 1.0f + e);
}

// ---------------------------------------------------------------------------
// A1 (float2-vectorized x loads — G13 finally applied to the conv):
// r18 proved the conv costs ~65us even as pure streaming -> the stall is the
// access pattern itself: 1 ch/thread = 4B scalar loads, ~3 requests per
// (channel,column), MSHR-swamped. Here: 2 ch/thread, float2 (8B/lane) loads
// -> request count per unit work HALVED.
// Block = (b, row h, chunk of 256 ch, column-half of 32 cols), 128 thr
// (2 waves), grid 3072 = 8 xcd x 64 rows x 3 chunks x 2 halves (slab
// swizzle keeps a row's 6 blocks on one XCD -> offpart write-merge + halo L2
// reuse). Batch = 4 columns (keeps window regs small; ~125 VGPR).
// Per 16-col quarter: stage gelu+x fp16 -> LDS, barrier, MFMA K=256
// (8 x mfma 16x16x32 per wave; wave0 = gelu x off_w planes n<8, wave1 =
// x x wt_w planes 8+n), store, barrier. Stores immediate (r8/r13 spill tell:
// WRITE_SIZE; expect ~7MB).
// ---------------------------------------------------------------------------
__global__ __launch_bounds__(128, 3) void dq_conv_mfma(
    const float* __restrict__ x,      // (B, N, C)
    const float* __restrict__ dw_w,   // (C, 9)
    const float* __restrict__ dw_b,   // (C,)
    const float* __restrict__ off_w,  // (8, C)
    const float* __restrict__ wt_w,   // (8, C)
    float* __restrict__ offpart)      // (NCHUNK, 16, B*N)
{
    __shared__ __attribute__((aligned(16))) _Float16 gl[16][272];  // 8.7 KB
    __shared__ __attribute__((aligned(16))) _Float16 xh[16][272];  // 8.7 KB
    const int t = threadIdx.x;
    const int lane = t & 63, wv = t >> 6;
    // ---- XCD-slab swizzle (bijective on 3072) ----
    const int xcd = blockIdx.x & 7;
    int local = blockIdx.x >> 3;               // 0..383
    const int chunk = local % 3; local /= 3;   // chunk fastest
    const int half = local & 1;  local >>= 1;  // then column-half
    const int r = xcd * (BB * HH / 8) + local; // row 0..511, slab per XCD
    const int h = r & (HH - 1);
    const int b = r >> 6;
    const int wstart = half * 32;
    const int c0 = chunk * CHUNK + 2 * t;      // this thread's 2 channels

    // ---- B fragments (fp16): wave0 = off_w, wave1 = wt_w (cols n<8 valid) ----
    const int n = lane & 15, kg = lane >> 4;
    const float* wsrc = (wv == 0) ? off_w : wt_w;
    half8 bfrag[8];
#pragma unroll
    for (int kt = 0; kt < 8; ++kt) {
        const bool valid = (n < 8);
        const float* src = wsrc + (valid ? n : 0) * CC + chunk * CHUNK + kt * 32 + kg * 8;
        half8 bf;
#pragma unroll
        for (int j = 0; j < 8; ++j) bf[j] = (_Float16)(valid ? src[j] : 0.f);
        bfrag[kt] = bf;
    }

    // conv weights for 2 channels
    float wA[9], wB[9];
#pragma unroll
    for (int j = 0; j < 9; ++j) { wA[j] = dw_w[c0 * 9 + j]; wB[j] = dw_w[(c0 + 1) * 9 + j]; }
    const float biasA = dw_b[c0], biasB = dw_b[c0 + 1];
    const bool tv = (h > 0), bv = (h < HH - 1);
    if (!tv) { wA[0] = wA[1] = wA[2] = 0.f; wB[0] = wB[1] = wB[2] = 0.f; }
    if (!bv) { wA[6] = wA[7] = wA[8] = 0.f; wB[6] = wB[7] = wB[8] = 0.f; }

    const float* base = x + (size_t)b * NN * CC + c0;
    const float* rT = base + (size_t)((tv ? h - 1 : 0) * WW) * CC;   // h-1 (clamped)
    const float* rM = base + (size_t)(h * WW) * CC;                  // h
    const float* rB = base + (size_t)((bv ? h + 1 : h) * WW) * CC;   // h+1 (clamped)

    float2 cT[4], cM[4], cB[4], nT[4], nM[4], nB[4];
    float2 pT, pM, pB;              // left-halo carry (col wstart-1)
    const float2 zz = make_float2(0.f, 0.f);
    if (half) {
        const size_t o = (size_t)(wstart - 1) * CC;
        pT = *(const float2*)&rT[o]; pM = *(const float2*)&rM[o]; pB = *(const float2*)&rB[o];
    } else { pT = zz; pM = zz; pB = zz; }
    float2 tT, tM, tB;              // right-halo tail (col wstart+32)
    if (!half) {
        const size_t o = (size_t)(wstart + 32) * CC;
        tT = *(const float2*)&rT[o]; tM = *(const float2*)&rM[o]; tB = *(const float2*)&rB[o];
    } else { tT = zz; tM = zz; tB = zz; }

#pragma unroll
    for (int j = 0; j < 4; ++j) {
        const size_t o = (size_t)(wstart + j) * CC;
        cT[j] = *(const float2*)&rT[o]; cM[j] = *(const float2*)&rM[o]; cB[j] = *(const float2*)&rB[o];
    }

#pragma unroll
    for (int wb = 0; wb < 8; ++wb) {           // 8 batches of 4 cols
        if (wb < 7) {
#pragma unroll
            for (int j = 0; j < 4; ++j) {
                const size_t o = (size_t)(wstart + wb * 4 + 4 + j) * CC;
                nT[j] = *(const float2*)&rT[o];
                nM[j] = *(const float2*)&rM[o];
                nB[j] = *(const float2*)&rB[o];
            }
        } else {
            nT[0] = tT; nM[0] = tM; nB[0] = tB;
#pragma unroll
            for (int j = 1; j < 4; ++j) { nT[j] = zz; nM[j] = zz; nB[j] = zz; }
        }
#pragma unroll
        for (int j = 0; j < 4; ++j) {
            const float2 lT = j ? cT[j - 1] : pT;
            const float2 lM = j ? cM[j - 1] : pM;
            const float2 lB = j ? cB[j - 1] : pB;
            const float2 rTv = (j == 3) ? nT[0] : cT[j + 1];
            const float2 rMv = (j == 3) ? nM[0] : cM[j + 1];
            const float2 rBv = (j == 3) ? nB[0] : cB[j + 1];
            const float convA = lT.x * wA[0] + cT[j].x * wA[1] + rTv.x * wA[2]
                              + lM.x * wA[3] + cM[j].x * wA[4] + rMv.x * wA[5]
                              + lB.x * wA[6] + cB[j].x * wA[7] + rBv.x * wA[8];
            const float convB = lT.y * wB[0] + cT[j].y * wB[1] + rTv.y * wB[2]
                              + lM.y * wB[3] + cM[j].y * wB[4] + rMv.y * wB[5]
                              + lB.y * wB[6] + cB[j].y * wB[7] + rBv.y * wB[8];
            const int colq = (wb & 3) * 4 + j;         // column within quarter
            half2f gv; gv[0] = (_Float16)gelu_fast(convA + biasA);
                       gv[1] = (_Float16)gelu_fast(convB + biasB);
            *(half2f*)&gl[colq][2 * t] = gv;
            half2f xv; xv[0] = (_Float16)cM[j].x; xv[1] = (_Float16)cM[j].y;
            *(half2f*)&xh[colq][2 * t] = xv;
        }
        pT = cT[3]; pM = cM[3]; pB = cB[3];
#pragma unroll
        for (int j = 0; j < 4; ++j) { cT[j] = nT[j]; cM[j] = nM[j]; cB[j] = nB[j]; }

        if ((wb & 3) == 3) {                   // end of 16-col quarter
            const int q = wb >> 2;
            __syncthreads();
            f32x4 acc = {0.f, 0.f, 0.f, 0.f};
            if (wv == 0) {
#pragma unroll
                for (int kt = 0; kt < 8; ++kt) {
                    const half8 a = *(const half8*)&gl[n][kt * 32 + kg * 8];
                    acc = __builtin_amdgcn_mfma_f32_16x16x32_f16(a, bfrag[kt], acc, 0, 0, 0);
                }
            } else {
#pragma unroll
                for (int kt = 0; kt < 8; ++kt) {
                    const half8 a = *(const half8*)&xh[n][kt * 32 + kg * 8];
                    acc = __builtin_amdgcn_mfma_f32_16x16x32_f16(a, bfrag[kt], acc, 0, 0, 0);
                }
            }
            // D: col n = plane (n<8 valid), rows kg*4..+3 = 4 consecutive cols
            if (n < 8) {
                const int plane = chunk * 16 + (wv ? 8 + n : n);
                const size_t gpos = (size_t)(b * NN) + h * WW + wstart + q * 16 + kg * 4;
                float4 st; st.x = acc[0]; st.y = acc[1]; st.z = acc[2]; st.w = acc[3];
                *(float4*)&offpart[(size_t)plane * (BB * NN) + gpos] = st;
            }
            if (wb < 7) __syncthreads();
        }
    }
}

// ---------------------------------------------------------------------------
// Combine (coalesced): sum 3 chunk partials, sigmoid gate, shift, clip.
// ---------------------------------------------------------------------------
__global__ __launch_bounds__(256) void dq_combine(
    const float* __restrict__ offpart,  // (NCHUNK, 16, B*N)
    const float* __restrict__ off_b,
    const float* __restrict__ wt_b,
    float* __restrict__ ixiy)           // (2, B*G, N)
{
    const int t = threadIdx.x;
    const int o = t >> 5;
    const int gpos = blockIdx.x * 32 + (t & 31);
    const int b = gpos >> 12;
    const int hw = gpos & 4095;
    const int h = hw >> 6, w = hw & 63;

    float so = 0.f, sw = 0.f;
#pragma unroll
    for (int ch = 0; ch < NCHUNK; ++ch) {
        so += offpart[((size_t)(ch * 16 + o)) * (BB * NN) + gpos];
        sw += offpart[((size_t)(ch * 16 + 8 + o)) * (BB * NN) + gpos];
    }
    const float sig = 1.f / (1.f + __expf(-(sw + wt_b[o])));
    const float val = (so + off_b[o]) * sig;

    if (o < 4) {
        const float shx = (o == 2) ? -1.f : ((o == 3) ? 1.f : 0.f);
        const float ix = fminf(fmaxf((float)w + val + shx, 0.f), (float)(WW - 1));
        ixiy[(b * GG + o) * NN + hw] = ix;
    } else {
        const int g = o - 4;
        const float shy = (g == 0) ? -1.f : ((g == 1) ? 1.f : 0.f);
        const float iy = fminf(fmaxf((float)h + val + shy, 0.f), (float)(HH - 1));
        ixiy[BB * GG * NN + (b * GG + g) * NN + hw] = iy;
    }
}

// ---------------------------------------------------------------------------
// B: bilinear border sampling, float4-vectorized, XCD-swizzled (T1).
// ---------------------------------------------------------------------------
__global__ __launch_bounds__(192) void dq_sample_vec(
    const float* __restrict__ x,        // (B, N, C)
    const float* __restrict__ ixiy,     // (2, B*G, N)
    float* __restrict__ out)            // (B, N, C)
{
    __shared__ float ixy[8];
    const int t = threadIdx.x;
    const int p = (blockIdx.x & 7) * (BB * NN / 8) + (blockIdx.x >> 3);
    const int b = p >> 12;
    const int hw = p & 4095;

    if (t < 8) {
        const int g = t & 3;
        const int plane = (t >> 2) * (BB * GG * NN);
        ixy[t] = ixiy[plane + (b * GG + g) * NN + hw];
    }
    __syncthreads();

    const int g = t / 48;
    const float ix = ixy[g], iy = ixy[4 + g];
    const float x0f = floorf(ix), y0f = floorf(iy);
    const float wx = ix - x0f, wy = iy - y0f;
    const int x0 = (int)x0f, y0 = (int)y0f;
    const int x1 = min(x0 + 1, WW - 1), y1 = min(y0 + 1, HH - 1);
    const int c4 = t * 4;
    const float* xb = x + (size_t)b * NN * CC;
    const float4 v00 = *(const float4*)(xb + (size_t)(y0 * WW + x0) * CC + c4);
    const float4 v01 = *(const float4*)(xb + (size_t)(y0 * WW + x1) * CC + c4);
    const float4 v10 = *(const float4*)(xb + (size_t)(y1 * WW + x0) * CC + c4);
    const float4 v11 = *(const float4*)(xb + (size_t)(y1 * WW + x1) * CC + c4);
    const float w00 = (1.f - wx) * (1.f - wy), w01 = wx * (1.f - wy);
    const float w10 = (1.f - wx) * wy,         w11 = wx * wy;
    float4 rr;
    rr.x = v00.x * w00 + v01.x * w01 + v10.x * w10 + v11.x * w11;
    rr.y = v00.y * w00 + v01.y * w01 + v10.y * w10 + v11.y * w11;
    rr.z = v00.z * w00 + v01.z * w01 + v10.z * w10 + v11.z * w11;
    rr.w = v00.w * w00 + v01.w * w01 + v10.w * w10 + v11.w * w11;
    *(float4*)(out + (size_t)p * CC + c4) = rr;
}

// ---------------------------------------------------------------------------
// Fallback (small ws): round-1 fused offsets kernel + scalar sampler.
// ---------------------------------------------------------------------------
__global__ __launch_bounds__(256) void dqshift_offsets_kernel(
    const float* __restrict__ x, const float* __restrict__ dw_w,
    const float* __restrict__ dw_b, const float* __restrict__ off_w,
    const float* __restrict__ off_b, const float* __restrict__ wt_w,
    const float* __restrict__ wt_b, float* __restrict__ ixiy)
{
    const int wave = threadIdx.x >> 6;
    const int lane = threadIdx.x & 63;
    const int p = blockIdx.x * 4 + wave;
    const int b = p >> 12;
    const int hw = p & 4095;
    const int h = hw >> 6;
    const int w = hw & 63;
    const float* xb = x + (size_t)b * NN * CC;
    float accO[8], accW[8];
#pragma unroll
    for (int o = 0; o < 8; ++o) { accO[o] = 0.f; accW[o] = 0.f; }
    for (int k = 0; k < CC / 64; ++k) {
        const int c = lane + (k << 6);
        float conv = 0.f, xc = 0.f;
#pragma unroll
        for (int dy = -1; dy <= 1; ++dy) {
            const int hh = h + dy;
            const bool vy = (hh >= 0) && (hh < HH);
#pragma unroll
            for (int dx = -1; dx <= 1; ++dx) {
                const int ww = w + dx;
                const bool vv = vy && (ww >= 0) && (ww < WW);
                const float tt = vv ? xb[(size_t)(hh * WW + ww) * CC + c] : 0.f;
                if (dy == 0 && dx == 0) xc = tt;
                conv = fmaf(tt, dw_w[c * 9 + (dy + 1) * 3 + (dx + 1)], conv);
            }
        }
        const float gv = conv + dw_b[c];
        const float gle = 0.5f * gv * (1.0f + erff(gv * 0.70710678118654752f));
#pragma unroll
        for (int o = 0; o < 8; ++o) {
            accO[o] = fmaf(gle, off_w[o * CC + c], accO[o]);
            accW[o] = fmaf(xc, wt_w[o * CC + c], accW[o]);
        }
    }
#pragma unroll
    for (int o = 0; o < 8; ++o) {
#pragma unroll
        for (int s = 32; s > 0; s >>= 1) {
            accO[o] += __shfl_xor(accO[o], s, 64);
            accW[o] += __shfl_xor(accW[o], s, 64);
        }
    }
    if (lane == 0) {
        const float shx[4] = {0.f, 0.f, -1.f, 1.f};
        const float shy[4] = {-1.f, 1.f, 0.f, 0.f};
#pragma unroll
        for (int g = 0; g < 4; ++g) {
            const float sx = 1.f / (1.f + expf(-(accW[g] + wt_b[g])));
            const float sy = 1.f / (1.f + expf(-(accW[4 + g] + wt_b[4 + g])));
            const float ox = (accO[g] + off_b[g]) * sx + shx[g];
            const float oy = (accO[4 + g] + off_b[4 + g]) * sy + shy[g];
            const float ix = fminf(fmaxf((float)w + ox, 0.f), (float)(WW - 1));
            const float iy = fminf(fmaxf((float)h + oy, 0.f), (float)(HH - 1));
            const int idx = (b * GG + g) * NN + hw;
            ixiy[idx] = ix;
            ixiy[BB * GG * NN + idx] = iy;
        }
    }
}

__global__ __launch_bounds__(256) void dqshift_sample_kernel(
    const float* __restrict__ x,
    const float* __restrict__ ixiy,
    float* __restrict__ out)
{
    const int p = blockIdx.x;
    const int b = p >> 12;
    const int hw = p & 4095;
    const float* xb = x + (size_t)b * NN * CC;
    float* ob = out + (size_t)p * CC;

#pragma unroll
    for (int k = 0; k < 3; ++k) {
        const int c = threadIdx.x + (k << 8);
        const int g = c / (CC / GG);
        const int idx = (b * GG + g) * NN + hw;
        const float ix = ixiy[idx];
        const float iy = ixiy[BB * GG * NN + idx];
        const float x0f = floorf(ix);
        const float y0f = floorf(iy);
        const float wx = ix - x0f;
        const float wy = iy - y0f;
        const int x0 = (int)x0f;
        const int y0 = (int)y0f;
        const int x1 = min(x0 + 1, WW - 1);
        const int y1 = min(y0 + 1, HH - 1);
        const float* r0 = xb + (size_t)(y0 * WW) * CC + c;
        const float* r1 = xb + (size_t)(y1 * WW) * CC + c;
        const float v00 = r0[(size_t)x0 * CC];
        const float v01 = r0[(size_t)x1 * CC];
        const float v10 = r1[(size_t)x0 * CC];
        const float v11 = r1[(size_t)x1 * CC];
        ob[c] = v00 * (1.f - wx) * (1.f - wy) + v01 * wx * (1.f - wy)
              + v10 * (1.f - wx) * wy + v11 * wx * wy;
    }
}

extern "C" void kernel_launch(void* const* d_in, const int* in_sizes, int n_in,
                              void* d_out, int out_size, void* d_ws, size_t ws_size,
                              hipStream_t stream) {
    const float* x     = (const float*)d_in[0];
    const float* dw_w  = (const float*)d_in[1];
    const float* dw_b  = (const float*)d_in[2];
    const float* off_w = (const float*)d_in[3];
    const float* off_b = (const float*)d_in[4];
    const float* wt_w  = (const float*)d_in[5];
    const float* wt_b  = (const float*)d_in[6];

    float* ixiy = (float*)d_ws;                              // 1 MiB
    float* offpart = (float*)d_ws + 2 * BB * GG * NN;        // 6.29 MiB
    const size_t need = (size_t)(2 * BB * GG * NN + NCHUNK * 16 * BB * NN) * 4;

    if (ws_size >= need) {
        dq_conv_mfma<<<BB * HH * NCHUNK * 2, 128, 0, stream>>>(
            x, dw_w, dw_b, off_w, wt_w, offpart);
        dq_combine<<<BB * NN / 32, 256, 0, stream>>>(
            offpart, off_b, wt_b, ixiy);
        dq_sample_vec<<<BB * NN, 192, 0, stream>>>(
            x, ixiy, (float*)d_out);
    } else {
        dqshift_offsets_kernel<<<BB * NN / 4, 256, 0, stream>>>(
            x, dw_w, dw_b, off_w, off_b, wt_w, wt_b, ixiy);
        dqshift_sample_kernel<<<BB * NN, 256, 0, stream>>>(x, ixiy, (float*)d_out);
    }
}